// Round 13
// baseline (169.253 us; speedup 1.0000x reference)
//
#include <hip/hip_runtime.h>
#include <hip/hip_bf16.h>

// N=524288, D=9, E=2, H=128, M=32, O=2, K=1.
// CONFIRMED: d_in fp32, d_out fp32 (N*2 + loss), ref = plain fp32 numpy on
// raw inputs; compare in bf16-cast space. Gates one-hot 1.0; loss from counts.
// R13: force the 24-words/j weight stream onto the SCALAR pipe via
// address_space(4) loads. Evidence (R11/R12): SGPR=80 (no weight data in
// SGPRs), VALUBusy ~50% == 26 VALU / (26 VALU + 24 VMEM) issue mix, 80us ~=
// 3072 broadcast global_load_dword/wave x 32 waves/CU on the TA unit. The
// weights are wave-uniform (12 KB shared by all waves) -> s_load/K$ frees
// the VMEM unit; VALU becomes the limit (~22us floor).
#define NTOK 524288
#define TPB  256
#define NBLK (NTOK / TPB)   // 2048

#define CAS __attribute__((address_space(4)))

__device__ __forceinline__ float bf2f(unsigned short u) {
    union { unsigned int i; float f; } v;
    v.i = ((unsigned int)u) << 16;
    return v.f;
}

// wave-uniform load through the constant address space -> guaranteed s_load
__device__ __forceinline__ float sld(const float* p, int i) {
    const CAS float* cp = (const CAS float*)p;
    return cp[i];
}

__device__ __forceinline__ float ldq(const void* p, int i, bool f32) {
    if (f32) return ((const float*)p)[i];
    return bf2f(((const unsigned short*)p)[i]);   // safety fallback
}

// ---------------------------------------------------------------------------
// Prep (1 block): parallel dtype detect, zero counters, stage w_gate + folded
// biases, pack weights interleaved per hidden unit j:
//   wpack[j*24 + e*12 + {0..8: W1[e][:,j], 9: b1[e][j], 10,11: (W2@Wout)[e][j]}]
//   bpp[e*2+o] = b2[e]@Wout[:,o] + bout[o]
// ---------------------------------------------------------------------------
__global__ void prep_kernel(const void* __restrict__ num_prop,
                            const void* __restrict__ wgate,
                            const void* __restrict__ W1,
                            const void* __restrict__ b1,
                            const void* __restrict__ W2,
                            const void* __restrict__ b2,
                            const void* __restrict__ Wout,
                            const void* __restrict__ bout,
                            unsigned int* __restrict__ cnt1,
                            unsigned int* __restrict__ done,
                            int* __restrict__ flag,
                            float* __restrict__ bpp,
                            float* __restrict__ wgf,
                            float* __restrict__ wpack)
{
    __shared__ int sbad;
    const int t = threadIdx.x;
    if (t == 0) { sbad = 0; *cnt1 = 0u; *done = 0u; }
    __syncthreads();
    if (t < 72) {   // parallel detect: bf16 N(0,1) exponents cluster near 127
        unsigned short u = ((const unsigned short*)num_prop)[t];
        int e = (u >> 7) & 0xFF;
        if (e < 64 || e > 191) sbad = 1;   // benign race: all writers store 1
    }
    __syncthreads();
    const bool f32 = (sbad != 0);
    if (t == 0) *flag = sbad;

    if (t < 18) wgf[t] = ldq(wgate, t, f32);

    if (t < 4) {  // bpp[e][o] = sum_m b2[e][m]*Wout[m][o] + bout[o]
        int e = t >> 1, o = t & 1;
        float acc = ldq(bout, o, f32);
        for (int m = 0; m < 32; ++m)
            acc += ldq(b2, e * 32 + m, f32) * ldq(Wout, m * 2 + o, f32);
        bpp[t] = acc;
    }

    const int e = t >> 7;       // 256 threads -> (e, j)
    const int j = t & 127;
    float p0 = 0.f, p1 = 0.f;
    for (int m = 0; m < 32; ++m) {
        float w = ldq(W2, (e * 128 + j) * 32 + m, f32);
        p0 += w * ldq(Wout, m * 2 + 0, f32);
        p1 += w * ldq(Wout, m * 2 + 1, f32);
    }
    float* dst = wpack + j * 24 + e * 12;
    #pragma unroll
    for (int d = 0; d < 9; ++d)
        dst[d] = ldq(W1, (e * 9 + d) * 128 + j, f32);
    dst[9]  = ldq(b1, e * 128 + j, f32);
    dst[10] = p0;
    dst[11] = p1;
}

// ---------------------------------------------------------------------------
// Main: one thread per token, x pinned in VGPRs; weights streamed via the
// SCALAR pipe (AS4 s_load). Dense-both experts; coalesced float2 store.
// Fused loss via last-block ticket.
// ---------------------------------------------------------------------------
__global__ __launch_bounds__(TPB, 8)
void moe_main(const void* __restrict__ xg,
              const int* __restrict__ flag,
              const float* __restrict__ wgf,
              const float* __restrict__ bpp,
              const float* __restrict__ wpack,
              unsigned int* __restrict__ cnt1,
              unsigned int* __restrict__ done,
              float2* __restrict__ out,
              float* __restrict__ loss_out)
{
    __shared__ unsigned int cblk;
    const int tid = threadIdx.x;
    if (tid == 0) cblk = 0u;
    __syncthreads();

    // x: global -> registers (one-time; HBM at 2% so stride-9 slack is free)
    const bool f32 = (*flag) != 0;
    const int base = blockIdx.x * (TPB * 9) + tid * 9;
    float x[9];
    if (f32) {
        const float* xf = (const float*)xg + base;
        #pragma unroll
        for (int d = 0; d < 9; ++d) x[d] = xf[d];
    } else {
        const unsigned short* xu = (const unsigned short*)xg + base;
        #pragma unroll
        for (int d = 0; d < 9; ++d) x[d] = bf2f(xu[d]);
    }
    // PIN: opaque VGPR definition -- no remat of x possible.
    #pragma unroll
    for (int d = 0; d < 9; ++d) asm volatile("" : "+v"(x[d]));

    // gating: fp32 fma dot, argmax (tie -> expert 0, stable top_k)
    float l0 = 0.f, l1 = 0.f;
    #pragma unroll
    for (int d = 0; d < 9; ++d) {
        l0 = fmaf(x[d], sld(wgf, d * 2 + 0), l0);
        l1 = fmaf(x[d], sld(wgf, d * 2 + 1), l1);
    }
    const bool e1 = l1 > l0;

    unsigned long long bal = __ballot(e1);
    if ((tid & 63) == 0)
        atomicAdd(&cblk, (unsigned int)__popcll(bal));

    // accumulators pre-seeded with folded bias per expert
    float a00 = sld(bpp, 0), a01 = sld(bpp, 1);
    float a10 = sld(bpp, 2), a11 = sld(bpp, 3);

    #pragma unroll 4
    for (int j = 0; j < 128; ++j) {
        const int wb = j * 24;              // uniform -> scalar pipe (s_load)
        float h0 = sld(wpack, wb + 9), h1 = sld(wpack, wb + 21);
        #pragma unroll
        for (int d = 0; d < 9; ++d) {
            h0 = fmaf(x[d], sld(wpack, wb + d),      h0);
            h1 = fmaf(x[d], sld(wpack, wb + 12 + d), h1);
        }
        h0 = fmaxf(h0, 0.f);
        h1 = fmaxf(h1, 0.f);
        a00 = fmaf(h0, sld(wpack, wb + 10), a00);
        a01 = fmaf(h0, sld(wpack, wb + 11), a01);
        a10 = fmaf(h1, sld(wpack, wb + 22), a10);
        a11 = fmaf(h1, sld(wpack, wb + 23), a11);
    }

    float2 o;
    o.x = e1 ? a10 : a00;
    o.y = e1 ? a11 : a01;
    out[blockIdx.x * TPB + tid] = o;   // coalesced 8B/lane

    // block count -> global; last-finished block computes the loss.
    __syncthreads();
    if (tid == 0) {
        atomicAdd(cnt1, cblk);
        __threadfence();
        unsigned int ticket = atomicAdd(done, 1u);
        if (ticket == (unsigned int)(NBLK - 1)) {
            // gates one-hot 1.0 -> importance == load == counts; cv^2 ddof=1:
            // var=(c0-c1)^2/2, mean=N/2; loss = 0.01*2*cv^2 (~1e-9).
            double c1 = (double)atomicAdd(cnt1, 0u);
            double c0 = (double)NTOK - c1;
            double diff = c0 - c1;
            double mean = (double)NTOK * 0.5;
            double cv2  = (0.5 * diff * diff) / (mean * mean + 1e-10);
            *loss_out = (float)(0.02 * cv2);
        }
    }
}

extern "C" void kernel_launch(void* const* d_in, const int* in_sizes, int n_in,
                              void* d_out, int out_size, void* d_ws, size_t ws_size,
                              hipStream_t stream) {
    const void* num_prop = d_in[0]; // [N,9] fp32
    // d_in[1] = cat_prop (unused)
    const void* w_gate   = d_in[2]; // [9,2]
    const void* W1       = d_in[3]; // [2,9,128]
    const void* b1       = d_in[4]; // [2,128]
    const void* W2       = d_in[5]; // [2,128,32]
    const void* b2       = d_in[6]; // [2,32]
    const void* Wout     = d_in[7]; // [32,2]
    const void* bout     = d_in[8]; // [2]
    // d_in[9] = k (==1)

    char* ws = (char*)d_ws;
    unsigned int* cnt1 = (unsigned int*)ws;          // @0
    unsigned int* done = (unsigned int*)(ws + 4);    // @4
    int* flag          = (int*)(ws + 8);             // @8
    float* bpp         = (float*)(ws + 32);          // 4 f
    float* wgf         = (float*)(ws + 64);          // 18 f
    float* wpack       = (float*)(ws + 192);         // 3072 f (interleaved)

    float*  outf = (float*)d_out;                    // fp32: N*2 + loss
    float2* out2 = (float2*)d_out;

    hipLaunchKernelGGL(prep_kernel, dim3(1), dim3(256), 0, stream,
                       num_prop, w_gate, W1, b1, W2, b2, Wout, bout,
                       cnt1, done, flag, bpp, wgf, wpack);
    hipLaunchKernelGGL(moe_main, dim3(NBLK), dim3(TPB), 0, stream,
                       num_prop, flag, wgf, bpp, wpack, cnt1, done,
                       out2, outf + (size_t)NTOK * 2);
}

// Round 14
// 168.738 us; speedup vs baseline: 1.0031x; 1.0031x over previous
//
#include <hip/hip_runtime.h>
#include <hip/hip_bf16.h>

// N=524288, D=9, E=2, H=128, M=32, O=2, K=1.
// CONFIRMED: d_in fp32, d_out fp32 (N*2 + loss), ref = plain fp32 numpy on
// raw inputs; compare in bf16-cast space. Gates one-hot 1.0; loss from counts.
// R14: float4 weight stream. Evidence R11-R13: kernel is VMEM-INSTRUCTION
// bound -- 32 waves/CU x 3072 broadcast global_load_dword ~= 98k TA instr
// ~= 80us @ ~2cyc/instr; VALUBusy pinned at issue-mix 26/(26+24)=50%.
// wpack's 24 floats/j are already 6 aligned 16B chunks -> load as float4
// (global_load_dwordx4): 6 VMEM/j, ~20us TA time ~= 22us VALU floor.
// FMA chains keep the exact R9 sequential order (bit-identical output).
#define NTOK 524288
#define TPB  256
#define NBLK (NTOK / TPB)   // 2048

__device__ __forceinline__ float bf2f(unsigned short u) {
    union { unsigned int i; float f; } v;
    v.i = ((unsigned int)u) << 16;
    return v.f;
}

__device__ __forceinline__ float ldq(const void* p, int i, bool f32) {
    if (f32) return ((const float*)p)[i];
    return bf2f(((const unsigned short*)p)[i]);   // safety fallback
}

// ---------------------------------------------------------------------------
// Prep (1 block): parallel dtype detect, zero counters, stage w_gate + folded
// biases, pack weights interleaved per hidden unit j (6 float4 chunks):
//   wpack[j*24 + e*12 + {0..8: W1[e][:,j], 9: b1[e][j], 10,11: (W2@Wout)[e][j]}]
//   bpp[e*2+o] = b2[e]@Wout[:,o] + bout[o]
// ---------------------------------------------------------------------------
__global__ void prep_kernel(const void* __restrict__ num_prop,
                            const void* __restrict__ wgate,
                            const void* __restrict__ W1,
                            const void* __restrict__ b1,
                            const void* __restrict__ W2,
                            const void* __restrict__ b2,
                            const void* __restrict__ Wout,
                            const void* __restrict__ bout,
                            unsigned int* __restrict__ cnt1,
                            unsigned int* __restrict__ done,
                            int* __restrict__ flag,
                            float* __restrict__ bpp,
                            float* __restrict__ wgf,
                            float* __restrict__ wpack)
{
    __shared__ int sbad;
    const int t = threadIdx.x;
    if (t == 0) { sbad = 0; *cnt1 = 0u; *done = 0u; }
    __syncthreads();
    if (t < 72) {   // parallel detect: bf16 N(0,1) exponents cluster near 127
        unsigned short u = ((const unsigned short*)num_prop)[t];
        int e = (u >> 7) & 0xFF;
        if (e < 64 || e > 191) sbad = 1;   // benign race: all writers store 1
    }
    __syncthreads();
    const bool f32 = (sbad != 0);
    if (t == 0) *flag = sbad;

    if (t < 18) wgf[t] = ldq(wgate, t, f32);

    if (t < 4) {  // bpp[e][o] = sum_m b2[e][m]*Wout[m][o] + bout[o]
        int e = t >> 1, o = t & 1;
        float acc = ldq(bout, o, f32);
        for (int m = 0; m < 32; ++m)
            acc += ldq(b2, e * 32 + m, f32) * ldq(Wout, m * 2 + o, f32);
        bpp[t] = acc;
    }

    const int e = t >> 7;       // 256 threads -> (e, j)
    const int j = t & 127;
    float p0 = 0.f, p1 = 0.f;
    for (int m = 0; m < 32; ++m) {
        float w = ldq(W2, (e * 128 + j) * 32 + m, f32);
        p0 += w * ldq(Wout, m * 2 + 0, f32);
        p1 += w * ldq(Wout, m * 2 + 1, f32);
    }
    float* dst = wpack + j * 24 + e * 12;
    #pragma unroll
    for (int d = 0; d < 9; ++d)
        dst[d] = ldq(W1, (e * 9 + d) * 128 + j, f32);
    dst[9]  = ldq(b1, e * 128 + j, f32);
    dst[10] = p0;
    dst[11] = p1;
}

// ---------------------------------------------------------------------------
// Main: one thread per token, x pinned in VGPRs; weights streamed as float4
// (global_load_dwordx4, 6 VMEM/j). Dense-both experts; coalesced float2
// store. Fused loss via last-block ticket.
// ---------------------------------------------------------------------------
__global__ __launch_bounds__(TPB, 8)
void moe_main(const void* __restrict__ xg,
              const int* __restrict__ flag,
              const float* __restrict__ wgf,
              const float* __restrict__ bpp,
              const float* __restrict__ wpack,
              unsigned int* __restrict__ cnt1,
              unsigned int* __restrict__ done,
              float2* __restrict__ out,
              float* __restrict__ loss_out)
{
    __shared__ unsigned int cblk;
    const int tid = threadIdx.x;
    if (tid == 0) cblk = 0u;
    __syncthreads();

    // x: global -> registers (one-time; HBM at 2% so stride-9 slack is free)
    const bool f32 = (*flag) != 0;
    const int base = blockIdx.x * (TPB * 9) + tid * 9;
    float x[9];
    if (f32) {
        const float* xf = (const float*)xg + base;
        #pragma unroll
        for (int d = 0; d < 9; ++d) x[d] = xf[d];
    } else {
        const unsigned short* xu = (const unsigned short*)xg + base;
        #pragma unroll
        for (int d = 0; d < 9; ++d) x[d] = bf2f(xu[d]);
    }
    // PIN: opaque VGPR definition -- no remat of x possible.
    #pragma unroll
    for (int d = 0; d < 9; ++d) asm volatile("" : "+v"(x[d]));

    // gating: fp32 fma dot, argmax (tie -> expert 0, stable top_k)
    float l0 = 0.f, l1 = 0.f;
    #pragma unroll
    for (int d = 0; d < 9; ++d) {
        l0 = fmaf(x[d], wgf[d * 2 + 0], l0);
        l1 = fmaf(x[d], wgf[d * 2 + 1], l1);
    }
    const bool e1 = l1 > l0;

    unsigned long long bal = __ballot(e1);
    if ((tid & 63) == 0)
        atomicAdd(&cblk, (unsigned int)__popcll(bal));

    // accumulators pre-seeded with folded bias per expert
    float a00 = bpp[0], a01 = bpp[1], a10 = bpp[2], a11 = bpp[3];

    const float4* wq = (const float4*)wpack;   // 6 chunks per j
    #pragma unroll 4
    for (int j = 0; j < 128; ++j) {
        const float4 c0 = wq[j * 6 + 0];   // e0: w0..w3
        const float4 c1 = wq[j * 6 + 1];   // e0: w4..w7
        const float4 c2 = wq[j * 6 + 2];   // e0: w8, b1, p0, p1
        const float4 c3 = wq[j * 6 + 3];   // e1: w0..w3
        const float4 c4 = wq[j * 6 + 4];   // e1: w4..w7
        const float4 c5 = wq[j * 6 + 5];   // e1: w8, b1, p0, p1

        float h0 = c2.y;                   // same chain order as R9
        h0 = fmaf(x[0], c0.x, h0);
        h0 = fmaf(x[1], c0.y, h0);
        h0 = fmaf(x[2], c0.z, h0);
        h0 = fmaf(x[3], c0.w, h0);
        h0 = fmaf(x[4], c1.x, h0);
        h0 = fmaf(x[5], c1.y, h0);
        h0 = fmaf(x[6], c1.z, h0);
        h0 = fmaf(x[7], c1.w, h0);
        h0 = fmaf(x[8], c2.x, h0);
        float h1 = c5.y;
        h1 = fmaf(x[0], c3.x, h1);
        h1 = fmaf(x[1], c3.y, h1);
        h1 = fmaf(x[2], c3.z, h1);
        h1 = fmaf(x[3], c3.w, h1);
        h1 = fmaf(x[4], c4.x, h1);
        h1 = fmaf(x[5], c4.y, h1);
        h1 = fmaf(x[6], c4.z, h1);
        h1 = fmaf(x[7], c4.w, h1);
        h1 = fmaf(x[8], c5.x, h1);

        h0 = fmaxf(h0, 0.f);
        h1 = fmaxf(h1, 0.f);
        a00 = fmaf(h0, c2.z, a00);
        a01 = fmaf(h0, c2.w, a01);
        a10 = fmaf(h1, c5.z, a10);
        a11 = fmaf(h1, c5.w, a11);
    }

    float2 o;
    o.x = e1 ? a10 : a00;
    o.y = e1 ? a11 : a01;
    out[blockIdx.x * TPB + tid] = o;   // coalesced 8B/lane

    // block count -> global; last-finished block computes the loss.
    __syncthreads();
    if (tid == 0) {
        atomicAdd(cnt1, cblk);
        __threadfence();
        unsigned int ticket = atomicAdd(done, 1u);
        if (ticket == (unsigned int)(NBLK - 1)) {
            // gates one-hot 1.0 -> importance == load == counts; cv^2 ddof=1:
            // var=(c0-c1)^2/2, mean=N/2; loss = 0.01*2*cv^2 (~1e-9).
            double c1 = (double)atomicAdd(cnt1, 0u);
            double c0 = (double)NTOK - c1;
            double diff = c0 - c1;
            double mean = (double)NTOK * 0.5;
            double cv2  = (0.5 * diff * diff) / (mean * mean + 1e-10);
            *loss_out = (float)(0.02 * cv2);
        }
    }
}

extern "C" void kernel_launch(void* const* d_in, const int* in_sizes, int n_in,
                              void* d_out, int out_size, void* d_ws, size_t ws_size,
                              hipStream_t stream) {
    const void* num_prop = d_in[0]; // [N,9] fp32
    // d_in[1] = cat_prop (unused)
    const void* w_gate   = d_in[2]; // [9,2]
    const void* W1       = d_in[3]; // [2,9,128]
    const void* b1       = d_in[4]; // [2,128]
    const void* W2       = d_in[5]; // [2,128,32]
    const void* b2       = d_in[6]; // [2,32]
    const void* Wout     = d_in[7]; // [32,2]
    const void* bout     = d_in[8]; // [2]
    // d_in[9] = k (==1)

    char* ws = (char*)d_ws;
    unsigned int* cnt1 = (unsigned int*)ws;          // @0
    unsigned int* done = (unsigned int*)(ws + 4);    // @4
    int* flag          = (int*)(ws + 8);             // @8
    float* bpp         = (float*)(ws + 32);          // 4 f
    float* wgf         = (float*)(ws + 64);          // 18 f
    float* wpack       = (float*)(ws + 192);         // 3072 f, 16B-aligned

    float*  outf = (float*)d_out;                    // fp32: N*2 + loss
    float2* out2 = (float2*)d_out;

    hipLaunchKernelGGL(prep_kernel, dim3(1), dim3(256), 0, stream,
                       num_prop, w_gate, W1, b1, W2, b2, Wout, bout,
                       cnt1, done, flag, bpp, wgf, wpack);
    hipLaunchKernelGGL(moe_main, dim3(NBLK), dim3(TPB), 0, stream,
                       num_prop, flag, wgf, bpp, wpack, cnt1, done,
                       out2, outf + (size_t)NTOK * 2);
}